// Round 11
// baseline (62.663 us; speedup 1.0000x reference)
//
#include <hip/hip_runtime.h>
#include <hip/hip_bf16.h>
#include <cstddef>

typedef __bf16 bf16;
typedef __bf16 bf16x4 __attribute__((ext_vector_type(4)));
typedef __bf16 bf16x8 __attribute__((ext_vector_type(8)));
typedef float  f32x4  __attribute__((ext_vector_type(4)));
typedef float  f32x16 __attribute__((ext_vector_type(16)));

#define NC   128
#define NS   6144
#define HD   32
#define BKV  64
#define NSPLIT 8
#define NCH  ((NS / NSPLIT) / BKV)    // 12 chunks per block
#define GELEMS (16 * NS)
// 32^-0.5 * log2(e): fold attention scale AND exp->exp2 conversion into Wq
#define QK_SCALE (0.17677669529663689f * 1.4426950408889634f)

__device__ __forceinline__ f32x4 mfma16(bf16x8 a, bf16x8 b, f32x4 c) {
  return __builtin_amdgcn_mfma_f32_16x16x32_bf16(a, b, c, 0, 0, 0);
}
__device__ __forceinline__ f32x16 mfma32(bf16x8 a, bf16x8 b, f32x16 c) {
  return __builtin_amdgcn_mfma_f32_32x32x16_bf16(a, b, c, 0, 0, 0);
}
// async global->LDS, 16B per lane; LDS dest = wave-uniform base + lane*16
__device__ __forceinline__ void gl16(const bf16* g, void* s) {
  __builtin_amdgcn_global_load_lds((const __attribute__((address_space(1))) void*)g,
                                   (__attribute__((address_space(3))) void*)s, 16, 0, 0);
}
// involution swizzle: spread 16B slots (bits[4:6]) by row bits (bits[7:9])
__device__ __forceinline__ int swz(int b) { return b ^ (((b >> 7) & 7) << 4); }
__device__ __forceinline__ unsigned cvtpk(float lo, float hi) {
  unsigned r;
  asm("v_cvt_pk_bf16_f32 %0, %1, %2" : "=v"(r) : "v"(lo), "v"(hi));
  return r;
}
__device__ __forceinline__ bf16x8 mkfrag(unsigned a, unsigned b, unsigned c, unsigned d) {
  union { unsigned u[4]; bf16x8 v; } t;
  t.u[0] = a; t.u[1] = b; t.u[2] = c; t.u[3] = d;
  return t.v;
}

// ---- fused: weight prep (blocks 0..191) + group-norm partial sums (192..287) ----
__global__ __launch_bounds__(256) void k_prep_stats(
    const float* __restrict__ qkv_w, const float* __restrict__ qkv_b,
    const float* __restrict__ proj_w, const float* __restrict__ x,
    bf16* __restrict__ wq, bf16* __restrict__ wp, float* __restrict__ bias_s,
    float* __restrict__ partials) {
  int bid = blockIdx.x;
  int tid = threadIdx.x;
  if (bid < 192) {
    int i = bid * 256 + tid;
    if (i < 3 * NC * NC) {
      float v = qkv_w[i];
      if (i < NC * NC) v *= QK_SCALE;
      wq[i] = (bf16)v;
    }
    if (i < NC * NC) wp[i] = (bf16)proj_w[i];
    if (i < 3 * NC) bias_s[i] = qkv_b[i] * ((i < NC) ? QK_SCALE : 1.0f);
    return;
  }
  int b = bid - 192;
  int g = b / 12, chunk = b % 12;
  float sum = 0.f, sq = 0.f;
  #pragma unroll
  for (int k = 0; k < 8; ++k) {
    int f4 = tid + k * 256;
    int c  = f4 >> 7;
    int s4 = f4 & 127;
    const float4 v = ((const float4*)x)[(size_t)(g * 16 + c) * (NS / 4) + chunk * 128 + s4];
    sum += v.x + v.y + v.z + v.w;
    sq  += v.x * v.x + v.y * v.y + v.z * v.z + v.w * v.w;
  }
  #pragma unroll
  for (int off = 32; off; off >>= 1) {
    sum += __shfl_down(sum, off, 64);
    sq  += __shfl_down(sq,  off, 64);
  }
  __shared__ float red[2][4];
  if ((tid & 63) == 0) { red[0][tid >> 6] = sum; red[1][tid >> 6] = sq; }
  __syncthreads();
  if (tid == 0) {
    partials[b * 2 + 0] = red[0][0] + red[0][1] + red[0][2] + red[0][3];
    partials[b * 2 + 1] = red[1][0] + red[1][1] + red[1][2] + red[1][3];
  }
}

// ---- fused GN-apply + QKV GEMM: xn tile built in LDS per block ----
// outputs: qg,kg [h][s][32]; v transposed vtg [h][c][s]
__global__ __launch_bounds__(256) void k_qkv(
    const float* __restrict__ x, const float* __restrict__ partials,
    const float* __restrict__ gn_w, const float* __restrict__ gn_b,
    const bf16* __restrict__ wq, const float* __restrict__ bias_s,
    bf16* __restrict__ qg, bf16* __restrict__ kg, bf16* __restrict__ vtg) {
  int ot = blockIdx.x;            // 0..5
  int st = blockIdx.y;            // 0..95
  int tid = threadIdx.x;
  __shared__ __align__(16) char xn[64 * 256];   // swizzled [s][c] bf16 tile
  __shared__ float swc[NC], sbc[NC];

  if (tid < NC) {
    int g = tid >> 4;
    float sum = 0.f, sq = 0.f;
    #pragma unroll
    for (int i = 0; i < 12; ++i) {
      sum += partials[(g * 12 + i) * 2 + 0];
      sq  += partials[(g * 12 + i) * 2 + 1];
    }
    float mean = sum * (1.0f / GELEMS);
    float var  = sq  * (1.0f / GELEMS) - mean * mean;
    float rstd = rsqrtf(var + 1e-5f);
    float wc = gn_w[tid] * rstd;
    swc[tid] = wc;
    sbc[tid] = gn_b[tid] - mean * wc;
  }
  __syncthreads();

  int s_local = tid & 63;
  int s_glob  = st * 64 + s_local;
  int wk = tid >> 6;
  #pragma unroll
  for (int i = 0; i < 4; ++i) {
    int c0 = (wk * 4 + i) * 8;
    bf16x8 ov;
    #pragma unroll
    for (int j = 0; j < 8; ++j) {
      int c = c0 + j;
      ov[j] = (bf16)(x[(size_t)c * NS + s_glob] * swc[c] + sbc[c]);
    }
    *(bf16x8*)(xn + ((s_local * 256 + c0 * 2) ^ ((s_local & 7) << 4))) = ov;
  }
  __syncthreads();

  int w = tid >> 6, l = tid & 63;
  int lr = l & 15, lg = l >> 4;
  int o_base = ot * 64 + (w >> 1) * 32;
  int sl_base = (w & 1) * 32;
  f32x4 acc[2][2] = {};
  #pragma unroll
  for (int k0 = 0; k0 < NC; k0 += 32) {
    bf16x8 a[2], b[2];
    #pragma unroll
    for (int m = 0; m < 2; ++m)
      a[m] = *(const bf16x8*)(wq + (size_t)(o_base + m * 16 + lr) * NC + k0 + lg * 8);
    #pragma unroll
    for (int n = 0; n < 2; ++n) {
      int row = sl_base + n * 16 + lr;
      b[n] = *(const bf16x8*)(xn + ((row * 256 + (k0 + lg * 8) * 2) ^ ((row & 7) << 4)));
    }
    #pragma unroll
    for (int m = 0; m < 2; ++m)
      #pragma unroll
      for (int n = 0; n < 2; ++n)
        acc[m][n] = mfma16(a[m], b[n], acc[m][n]);
  }
  #pragma unroll
  for (int m = 0; m < 2; ++m)
    #pragma unroll
    for (int n = 0; n < 2; ++n)
      #pragma unroll
      for (int r = 0; r < 4; ++r) {
        int o = o_base + m * 16 + lg * 4 + r;
        int s = st * 64 + sl_base + n * 16 + lr;
        float v = acc[m][n][r] + bias_s[o];
        int rem = o & 127, head = rem >> 5, c32 = rem & 31;
        if (o < NC)          qg[((size_t)head * NS + s) * HD + c32] = (bf16)v;
        else if (o < 2 * NC) kg[((size_t)head * NS + s) * HD + c32] = (bf16)v;
        else                 vtg[((size_t)head * HD + c32) * NS + s] = (bf16)v;
      }
}

// ---- flash attention: 32x32 MFMA, 32 q-rows/wave, in-register P (no P LDS),
//      fixed-m softmax, double-buffered K/V staging, split-KV x8 ----
__global__ __launch_bounds__(256, 6) void k_attn(
    const bf16* __restrict__ qg, const bf16* __restrict__ kg, const bf16* __restrict__ vtg,
    bf16* __restrict__ accP, float* __restrict__ ml) {
  const int h = blockIdx.y, sp = blockIdx.z;
  const int tid = threadIdx.x;
  const int w = tid >> 6, l = tid & 63;
  const int l31 = l & 31, hi = l >> 5;
  const int qrow0 = blockIdx.x * 128 + w * 32;

  __shared__ __align__(16) char kbuf[2][4096];   // K chunk [64 key][32 c], swizzled
  __shared__ __align__(16) char vbuf[2][4096];   // V^T chunk [32 c][64 key], swizzled

  const bf16* qp = qg + (size_t)h * NS * HD;
  const bf16* kp = kg + (size_t)h * NS * HD;
  const bf16* vp = vtg + (size_t)h * HD * NS;

  // Q as B operand of mfma(K,Q): lane holds Q[qrow0+l31][s*16 + hi*8 + j]
  bf16x8 qf0 = *(const bf16x8*)(qp + (size_t)(qrow0 + l31) * HD + hi * 8);
  bf16x8 qf1 = *(const bf16x8*)(qp + (size_t)(qrow0 + l31) * HD + 16 + hi * 8);

  // LDS read addresses (loop-invariant, pre-swizzled)
  const int kkey = ((l31 >> 1) & 7) << 4;
  const int ka0 = (l31 * 64 + hi * 16) ^ kkey;        // kt0 slice0; +32^ for slice1
  const int ka1 = (l31 * 64 + 32 + hi * 16) ^ kkey;
  const int vkey = (l31 & 7) << 4;
  const int vbase = l31 * 128 + hi * 8;

  f32x16 Ot = {};                    // O^T: col q = l31, rows c (never rescaled)
  float l_r = 0.f;                   // per-lane l partial (this lane's 32 keys/chunk)
  const f32x16 zed16 = {};
  const int kv_beg = sp * (NS / NSPLIT);

  // staging source mapping (pre-swizzled involution, validated R5-R10)
  const int o_st = w * 1024 + (l << 4);
  const int u_st = swz(o_st);
  const bf16* ksrc = kp + (size_t)(kv_beg + (u_st >> 6)) * HD + ((u_st & 63) >> 1);
  const bf16* vsrc = vp + (size_t)(u_st >> 7) * NS + kv_beg + ((u_st & 127) >> 1);

  f32x16 sv0, sv1;
  bf16x8 pf0, pf1, pf2, pf3;         // P^T B-frags for PV slices ks=0..3

  // fixed-m softmax + pack: sv reg r holds S[key_rel=(r&3)+8*(r>>2)+4*hi][q=l31];
  // frag element j of sub-slices maps to reg r=j (sub0) / r=8+j (sub1) -- lane-local.
  auto packP = [&](f32x16& sv, bf16x8& fA, bf16x8& fB) {
    #pragma unroll
    for (int r = 0; r < 16; ++r) sv[r] = __builtin_amdgcn_exp2f(sv[r]);
    l_r += (((sv[0] + sv[1]) + (sv[2] + sv[3])) + ((sv[4] + sv[5]) + (sv[6] + sv[7])))
         + (((sv[8] + sv[9]) + (sv[10] + sv[11])) + ((sv[12] + sv[13]) + (sv[14] + sv[15])));
    fA = mkfrag(cvtpk(sv[0], sv[1]),  cvtpk(sv[2], sv[3]),
                cvtpk(sv[4], sv[5]),  cvtpk(sv[6], sv[7]));
    fB = mkfrag(cvtpk(sv[8], sv[9]),  cvtpk(sv[10], sv[11]),
                cvtpk(sv[12], sv[13]), cvtpk(sv[14], sv[15]));
  };
  // V A-frag for slice ks: elements j = V^T[c=l31][key kt*32+sub*16+(j>>2)*8+4hi+(j&3)]
  // (same key order as pf -- contraction consistent); two 8B reads per frag.
  auto vfrag = [&](const char* vb, int ks) {
    int a_lin = vbase + ks * 32;
    union { bf16x4 h4[2]; bf16x8 v8; } vv;
    vv.h4[0] = *(const bf16x4*)(vb + (a_lin ^ vkey));
    vv.h4[1] = *(const bf16x4*)(vb + ((a_lin + 16) ^ vkey));
    return vv.v8;
  };

  // prologue: stage K(0), V(0), K(1); QK(0) + pack(0)
  gl16(ksrc, kbuf[0] + w * 1024);
  gl16(vsrc, vbuf[0] + w * 1024);
  gl16(ksrc + BKV * HD, kbuf[1] + w * 1024);
  __syncthreads();
  {
    const char* kb = kbuf[0];
    sv0 = mfma32(*(const bf16x8*)(kb + ka0), qf0, zed16);
    sv0 = mfma32(*(const bf16x8*)(kb + ka1), qf1, sv0);
    sv1 = mfma32(*(const bf16x8*)(kb + ka0 + 2048), qf0, zed16);
    sv1 = mfma32(*(const bf16x8*)(kb + ka1 + 2048), qf1, sv1);
  }
  packP(sv0, pf0, pf1);
  packP(sv1, pf2, pf3);

  for (int t = 0; t < NCH; ++t) {
    const int cur = t & 1, nxt = cur ^ 1;
    const bool hn = (t + 1 < NCH);
    __syncthreads();
    // staging at chunk top (drain at next barrier sees chunk-old loads)
    if (hn) gl16(vsrc + (size_t)(t + 1) * BKV, vbuf[nxt] + w * 1024);
    if (t + 2 < NCH) gl16(ksrc + (size_t)(t + 2) * BKV * HD, kbuf[cur] + w * 1024);
    __builtin_amdgcn_s_setprio(1);
    // PV(t): V from vbuf[cur], P^T frags from registers (packed last iteration)
    {
      const char* vb = vbuf[cur];
      Ot = mfma32(vfrag(vb, 0), pf0, Ot);
      Ot = mfma32(vfrag(vb, 1), pf1, Ot);
      Ot = mfma32(vfrag(vb, 2), pf2, Ot);
      Ot = mfma32(vfrag(vb, 3), pf3, Ot);
    }
    // QK(t+1): kbuf[nxt]
    if (hn) {
      const char* kb = kbuf[nxt];
      sv0 = mfma32(*(const bf16x8*)(kb + ka0), qf0, zed16);
      sv0 = mfma32(*(const bf16x8*)(kb + ka1), qf1, sv0);
      sv1 = mfma32(*(const bf16x8*)(kb + ka0 + 2048), qf0, zed16);
      sv1 = mfma32(*(const bf16x8*)(kb + ka1 + 2048), qf1, sv1);
    }
    __builtin_amdgcn_s_setprio(0);
    if (hn) {
      packP(sv0, pf0, pf1);
      packP(sv1, pf2, pf3);
    }
  }

  // this lane holds 32 of the 64 keys/chunk; partner lane l^32 holds the rest
  l_r += __shfl_xor(l_r, 32, 64);

  // store unnormalized O^T partials, layout [h][sp][cg(8)][s][4] bf16
  // O^T reg r: c = (r&3) + 8*(r>>2) + 4*hi -> cg = hi + 2*(r>>2), idx = r&3
  bf16* base = accP + (size_t)(h * NSPLIT + sp) * 8 * NS * 4;
  size_t qrow = qrow0 + l31;
  #pragma unroll
  for (int m = 0; m < 4; ++m) {
    bf16x4 ov;
    #pragma unroll
    for (int j = 0; j < 4; ++j) ov[j] = (bf16)Ot[4 * m + j];
    *(bf16x4*)(base + ((size_t)(hi + 2 * m) * NS + qrow) * 4) = ov;
  }
  if (hi == 0)
    ml[(size_t)(h * NSPLIT + sp) * NS + qrow] = l_r;
}

// ---- fused combine (plain sum: fixed-m) + proj GEMM + bias + residual + mask ----
__global__ __launch_bounds__(256) void k_proj(
    const bf16* __restrict__ wp, const bf16* __restrict__ accP, const float* __restrict__ ml,
    const float* __restrict__ proj_b, const float* __restrict__ x,
    const float* __restrict__ mask, float* __restrict__ out) {
  int ot = blockIdx.x;            // 0..1
  int st = blockIdx.y;            // 0..95
  int tid = threadIdx.x;
  __shared__ __align__(16) char at[64 * 256];   // swizzled [s][c] bf16 tile

  int s_local = tid & 63;
  int s = st * 64 + s_local;
  int wk = tid >> 6;
  if (ot == 0 && tid < 64)        // mask passthrough (second output)
    out[(size_t)NC * NS + st * 64 + tid] = mask[st * 64 + tid];
  #pragma unroll
  for (int i = 0; i < 4; ++i) {
    int c0 = (wk * 4 + i) * 8;
    int h = c0 >> 5;
    float L = 0.f;
    #pragma unroll
    for (int spl = 0; spl < NSPLIT; ++spl)
      L += ml[(size_t)(h * NSPLIT + spl) * NS + s];
    float inv = 1.0f / L;
    float o[8] = {};
    int cg0 = (c0 & 31) >> 2;
    #pragma unroll
    for (int spl = 0; spl < NSPLIT; ++spl) {
      const bf16* bp = accP + ((size_t)((h * NSPLIT + spl) * 8 + cg0) * NS + s) * 4;
      bf16x4 a0 = *(const bf16x4*)(bp);
      bf16x4 a1 = *(const bf16x4*)(bp + (size_t)NS * 4);
      #pragma unroll
      for (int j = 0; j < 4; ++j) {
        o[j]     += (float)a0[j];
        o[4 + j] += (float)a1[j];
      }
    }
    bf16x8 ov;
    #pragma unroll
    for (int j = 0; j < 8; ++j) ov[j] = (bf16)(o[j] * inv);
    *(bf16x8*)(at + ((s_local * 256 + c0 * 2) ^ ((s_local & 7) << 4))) = ov;
  }
  __syncthreads();

  int w = tid >> 6, l = tid & 63;
  int lr = l & 15, lg = l >> 4;
  int o_base = ot * 64 + (w >> 1) * 32;
  int sl_base = (w & 1) * 32;
  f32x4 acc[2][2] = {};
  #pragma unroll
  for (int k0 = 0; k0 < NC; k0 += 32) {
    bf16x8 a[2], b[2];
    #pragma unroll
    for (int m = 0; m < 2; ++m)
      a[m] = *(const bf16x8*)(wp + (size_t)(o_base + m * 16 + lr) * NC + k0 + lg * 8);
    #pragma unroll
    for (int n = 0; n < 2; ++n) {
      int row = sl_base + n * 16 + lr;
      b[n] = *(const bf16x8*)(at + ((row * 256 + (k0 + lg * 8) * 2) ^ ((row & 7) << 4)));
    }
    #pragma unroll
    for (int m = 0; m < 2; ++m)
      #pragma unroll
      for (int n = 0; n < 2; ++n)
        acc[m][n] = mfma16(a[m], b[n], acc[m][n]);
  }
  #pragma unroll
  for (int m = 0; m < 2; ++m)
    #pragma unroll
    for (int n = 0; n < 2; ++n)
      #pragma unroll
      for (int r = 0; r < 4; ++r) {
        int o = o_base + m * 16 + lg * 4 + r;
        int sg = st * 64 + sl_base + n * 16 + lr;
        float v = acc[m][n][r] + proj_b[o] + x[(size_t)o * NS + sg];
        out[(size_t)o * NS + sg] = v * mask[sg];
      }
}

extern "C" void kernel_launch(void* const* d_in, const int* in_sizes, int n_in,
                              void* d_out, int out_size, void* d_ws, size_t ws_size,
                              hipStream_t stream) {
  const float* x      = (const float*)d_in[0];
  const float* mask   = (const float*)d_in[1];
  const float* gn_w   = (const float*)d_in[2];
  const float* gn_b   = (const float*)d_in[3];
  const float* qkv_w  = (const float*)d_in[4];
  const float* qkv_b  = (const float*)d_in[5];
  const float* proj_w = (const float*)d_in[6];
  const float* proj_b = (const float*)d_in[7];

  char* ws = (char*)d_ws;
  float* partials = (float*)(ws + 0);            //     768 B
  float* bias_s   = (float*)(ws + 1024);         //    1536 B
  bf16*  wq       = (bf16*)(ws + 4096);          //   98304 B
  bf16*  wp       = (bf16*)(ws + 102400);        //   32768 B
  bf16*  qg       = (bf16*)(ws + 135168);        // 1.50 MB [h][s][32]
  bf16*  kg       = (bf16*)(ws + 1708032);       // 1.50 MB [h][s][32]
  bf16*  vtg      = (bf16*)(ws + 3280896);       // 1.50 MB [h][c][s]
  bf16*  accP     = (bf16*)(ws + 4853760);       // 12.58 MB [h][sp][cg][s][4]
  float* ml       = (float*)(ws + 17436672);     // 786 KB   [h][sp][s]
  float* out      = (float*)d_out;

  k_prep_stats<<<288, 256, 0, stream>>>(qkv_w, qkv_b, proj_w, x, wq, wp, bias_s, partials);
  k_qkv       <<<dim3(6, 96), 256, 0, stream>>>(x, partials, gn_w, gn_b, wq, bias_s, qg, kg, vtg);
  k_attn      <<<dim3(48, 4, NSPLIT), 256, 0, stream>>>(qg, kg, vtg, accP, ml);
  k_proj      <<<dim3(2, 96), 256, 0, stream>>>(wp, accP, ml, proj_b, x, mask, out);
}

// Round 12
// 61.519 us; speedup vs baseline: 1.0186x; 1.0186x over previous
//
#include <hip/hip_runtime.h>
#include <hip/hip_bf16.h>
#include <cstddef>

typedef __bf16 bf16;
typedef __bf16 bf16x4 __attribute__((ext_vector_type(4)));
typedef __bf16 bf16x8 __attribute__((ext_vector_type(8)));
typedef float  f32x4  __attribute__((ext_vector_type(4)));

#define NC   128
#define NS   6144
#define HD   32
#define BKV  64
#define NSPLIT 4
#define NCH  ((NS / NSPLIT) / BKV)    // 24 chunks per block
#define GELEMS (16 * NS)
// 32^-0.5 * log2(e): fold attention scale AND exp->exp2 conversion into Wq
#define QK_SCALE (0.17677669529663689f * 1.4426950408889634f)

__device__ __forceinline__ f32x4 mfma16(bf16x8 a, bf16x8 b, f32x4 c) {
  return __builtin_amdgcn_mfma_f32_16x16x32_bf16(a, b, c, 0, 0, 0);
}
// async global->LDS, 16B per lane; LDS dest = wave-uniform base + lane*16
__device__ __forceinline__ void gl16(const bf16* g, void* s) {
  __builtin_amdgcn_global_load_lds((const __attribute__((address_space(1))) void*)g,
                                   (__attribute__((address_space(3))) void*)s, 16, 0, 0);
}
// involution swizzle: spread 16B slots (bits[4:6]) by row bits (bits[7:9])
__device__ __forceinline__ int swz(int b) { return b ^ (((b >> 7) & 7) << 4); }

// ---- fused: weight prep (blocks 0..191) + group-norm partial sums (192..287) ----
__global__ __launch_bounds__(256) void k_prep_stats(
    const float* __restrict__ qkv_w, const float* __restrict__ qkv_b,
    const float* __restrict__ proj_w, const float* __restrict__ x,
    bf16* __restrict__ wq, bf16* __restrict__ wp, float* __restrict__ bias_s,
    float* __restrict__ partials) {
  int bid = blockIdx.x;
  int tid = threadIdx.x;
  if (bid < 192) {
    int i = bid * 256 + tid;
    if (i < 3 * NC * NC) {
      float v = qkv_w[i];
      if (i < NC * NC) v *= QK_SCALE;
      wq[i] = (bf16)v;
    }
    if (i < NC * NC) wp[i] = (bf16)proj_w[i];
    if (i < 3 * NC) bias_s[i] = qkv_b[i] * ((i < NC) ? QK_SCALE : 1.0f);
    return;
  }
  int b = bid - 192;
  int g = b / 12, chunk = b % 12;
  float sum = 0.f, sq = 0.f;
  #pragma unroll
  for (int k = 0; k < 8; ++k) {
    int f4 = tid + k * 256;
    int c  = f4 >> 7;
    int s4 = f4 & 127;
    const float4 v = ((const float4*)x)[(size_t)(g * 16 + c) * (NS / 4) + chunk * 128 + s4];
    sum += v.x + v.y + v.z + v.w;
    sq  += v.x * v.x + v.y * v.y + v.z * v.z + v.w * v.w;
  }
  #pragma unroll
  for (int off = 32; off; off >>= 1) {
    sum += __shfl_down(sum, off, 64);
    sq  += __shfl_down(sq,  off, 64);
  }
  __shared__ float red[2][4];
  if ((tid & 63) == 0) { red[0][tid >> 6] = sum; red[1][tid >> 6] = sq; }
  __syncthreads();
  if (tid == 0) {
    partials[b * 2 + 0] = red[0][0] + red[0][1] + red[0][2] + red[0][3];
    partials[b * 2 + 1] = red[1][0] + red[1][1] + red[1][2] + red[1][3];
  }
}

// ---- fused GN-apply + QKV GEMM: xn tile built in LDS per block ----
// outputs: qg,kg [h][s][32]; v transposed vtg [h][c][s]
__global__ __launch_bounds__(256) void k_qkv(
    const float* __restrict__ x, const float* __restrict__ partials,
    const float* __restrict__ gn_w, const float* __restrict__ gn_b,
    const bf16* __restrict__ wq, const float* __restrict__ bias_s,
    bf16* __restrict__ qg, bf16* __restrict__ kg, bf16* __restrict__ vtg) {
  int ot = blockIdx.x;            // 0..5
  int st = blockIdx.y;            // 0..95
  int tid = threadIdx.x;
  __shared__ __align__(16) char xn[64 * 256];   // swizzled [s][c] bf16 tile
  __shared__ float swc[NC], sbc[NC];

  if (tid < NC) {
    int g = tid >> 4;
    float sum = 0.f, sq = 0.f;
    #pragma unroll
    for (int i = 0; i < 12; ++i) {
      sum += partials[(g * 12 + i) * 2 + 0];
      sq  += partials[(g * 12 + i) * 2 + 1];
    }
    float mean = sum * (1.0f / GELEMS);
    float var  = sq  * (1.0f / GELEMS) - mean * mean;
    float rstd = rsqrtf(var + 1e-5f);
    float wc = gn_w[tid] * rstd;
    swc[tid] = wc;
    sbc[tid] = gn_b[tid] - mean * wc;
  }
  __syncthreads();

  int s_local = tid & 63;
  int s_glob  = st * 64 + s_local;
  int wk = tid >> 6;
  #pragma unroll
  for (int i = 0; i < 4; ++i) {
    int c0 = (wk * 4 + i) * 8;
    bf16x8 ov;
    #pragma unroll
    for (int j = 0; j < 8; ++j) {
      int c = c0 + j;
      ov[j] = (bf16)(x[(size_t)c * NS + s_glob] * swc[c] + sbc[c]);
    }
    *(bf16x8*)(xn + ((s_local * 256 + c0 * 2) ^ ((s_local & 7) << 4))) = ov;
  }
  __syncthreads();

  int w = tid >> 6, l = tid & 63;
  int lr = l & 15, lg = l >> 4;
  int o_base = ot * 64 + (w >> 1) * 32;
  int sl_base = (w & 1) * 32;
  f32x4 acc[2][2] = {};
  #pragma unroll
  for (int k0 = 0; k0 < NC; k0 += 32) {
    bf16x8 a[2], b[2];
    #pragma unroll
    for (int m = 0; m < 2; ++m)
      a[m] = *(const bf16x8*)(wq + (size_t)(o_base + m * 16 + lr) * NC + k0 + lg * 8);
    #pragma unroll
    for (int n = 0; n < 2; ++n) {
      int row = sl_base + n * 16 + lr;
      b[n] = *(const bf16x8*)(xn + ((row * 256 + (k0 + lg * 8) * 2) ^ ((row & 7) << 4)));
    }
    #pragma unroll
    for (int m = 0; m < 2; ++m)
      #pragma unroll
      for (int n = 0; n < 2; ++n)
        acc[m][n] = mfma16(a[m], b[n], acc[m][n]);
  }
  #pragma unroll
  for (int m = 0; m < 2; ++m)
    #pragma unroll
    for (int n = 0; n < 2; ++n)
      #pragma unroll
      for (int r = 0; r < 4; ++r) {
        int o = o_base + m * 16 + lg * 4 + r;
        int s = st * 64 + sl_base + n * 16 + lr;
        float v = acc[m][n][r] + bias_s[o];
        int rem = o & 127, head = rem >> 5, c32 = rem & 31;
        if (o < NC)          qg[((size_t)head * NS + s) * HD + c32] = (bf16)v;
        else if (o < 2 * NC) kg[((size_t)head * NS + s) * HD + c32] = (bf16)v;
        else                 vtg[((size_t)head * HD + c32) * NS + s] = (bf16)v;
      }
}

// ---- flash attention: fixed-m softmax, staging at chunk top, NO setprio,
//      l computed via ones-MFMA (matrix pipe) instead of VALU add chain ----
__global__ __launch_bounds__(256, 6) void k_attn(
    const bf16* __restrict__ qg, const bf16* __restrict__ kg, const bf16* __restrict__ vtg,
    bf16* __restrict__ accP, float* __restrict__ ml) {
  const int h = blockIdx.y, sp = blockIdx.z;
  const int tid = threadIdx.x;
  const int w = tid >> 6, l = tid & 63;
  const int lr = l & 15, lg = l >> 4;
  const int qrow0 = blockIdx.x * 64 + w * 16;

  __shared__ __align__(16) char kbuf[2][4096];   // K chunk [64 key][32 c], swizzled
  __shared__ __align__(16) char vbuf[2][4096];   // V^T chunk [32 c][64 key], swizzled
  __shared__ __align__(16) char pbs[4][2048];    // per-wave P^T tile [16 q][64 key]
  char* pw = pbs[w];
  const int pswz  = (lr & 7) << 4;
  const int wbase = lr * 128 + lg * 8;
  const int rbase = lr * 128 + lg * 16;
  const int kswz  = ((lr >> 1) & 7) << 4;
  const int vswz  = (lr & 7) << 4;

  const bf16* qp = qg + (size_t)h * NS * HD;
  const bf16* kp = kg + (size_t)h * NS * HD;
  const bf16* vp = vtg + (size_t)h * HD * NS;

  bf16x8 qf = *(const bf16x8*)(qp + (size_t)(qrow0 + lr) * HD + lg * 8);

  // ones A-fragment for the l-sum MFMA
  bf16x8 ones;
  #pragma unroll
  for (int j = 0; j < 8; ++j) ones[j] = (bf16)1.0f;

  f32x4 acc0 = {}, acc1 = {};          // O^T: rows c, col q = lr; never rescaled
  f32x4 lacc = {};                     // rows all equal: l[q=lr]
  const f32x4 zed = {};
  const int kv_beg = sp * (NS / NSPLIT);

  // staging source mapping (pre-swizzled involution, validated R5-R10)
  const int o_st = w * 1024 + (l << 4);
  const int u_st = swz(o_st);
  const bf16* ksrc = kp + (size_t)(kv_beg + (u_st >> 6)) * HD + ((u_st & 63) >> 1);
  const bf16* vsrc = vp + (size_t)(u_st >> 7) * NS + kv_beg + ((u_st & 127) >> 1);

  f32x4 sv[4];
  // fixed-m softmax: P = exp2(S), pack P^T to per-wave LDS (l handled by MFMA)
  auto softmax_p = [&]() {
    #pragma unroll
    for (int t4 = 0; t4 < 4; ++t4) {
      #pragma unroll
      for (int r = 0; r < 4; ++r) sv[t4][r] = __builtin_amdgcn_exp2f(sv[t4][r]);
      bf16x4 pk;
      pk[0] = (bf16)sv[t4][0]; pk[1] = (bf16)sv[t4][1];
      pk[2] = (bf16)sv[t4][2]; pk[3] = (bf16)sv[t4][3];
      *(bf16x4*)(pw + ((wbase + t4 * 32) ^ pswz)) = pk;
    }
  };

  // prologue: stage K(0), V(0), K(1); compute QK(0)+softmax(0)+P(0)
  gl16(ksrc, kbuf[0] + w * 1024);
  gl16(vsrc, vbuf[0] + w * 1024);
  gl16(ksrc + BKV * HD, kbuf[1] + w * 1024);
  __syncthreads();
  #pragma unroll
  for (int t4 = 0; t4 < 4; ++t4) {
    bf16x8 kf = *(const bf16x8*)(kbuf[0] + (((t4 * 16 + lr) * 64 + lg * 16) ^ kswz));
    sv[t4] = mfma16(kf, qf, zed);
  }
  softmax_p();

  for (int t = 0; t < NCH; ++t) {
    const int cur = t & 1, nxt = cur ^ 1;
    const bool hn = (t + 1 < NCH);
    __syncthreads();
    // ALL staging at chunk top: drain at next barrier sees chunk-old loads.
    if (hn) gl16(vsrc + (size_t)(t + 1) * BKV, vbuf[nxt] + w * 1024);
    if (t + 2 < NCH) gl16(ksrc + (size_t)(t + 2) * BKV * HD, kbuf[cur] + w * 1024);
    // QK(t+1): independent of PV(t); MFMAs pipeline together
    if (hn) {
      #pragma unroll
      for (int t4 = 0; t4 < 4; ++t4) {
        bf16x8 kf = *(const bf16x8*)(kbuf[nxt] + (((t4 * 16 + lr) * 64 + lg * 16) ^ kswz));
        sv[t4] = mfma16(kf, qf, zed);
      }
    }
    // PV(t) + l-sum: P(t) from this wave's LDS tile, V(t) from vbuf[cur]
    {
      const char* vb = vbuf[cur];
      bf16x8 pf0 = *(const bf16x8*)(pw + ((rbase + 0)  ^ pswz));
      bf16x8 pf1 = *(const bf16x8*)(pw + ((rbase + 64) ^ pswz));
      bf16x8 v00 = *(const bf16x8*)(vb + ((lr * 128 + 0  + lg * 16) ^ vswz));
      bf16x8 v10 = *(const bf16x8*)(vb + (((16 + lr) * 128 + 0  + lg * 16) ^ vswz));
      bf16x8 v01 = *(const bf16x8*)(vb + ((lr * 128 + 64 + lg * 16) ^ vswz));
      bf16x8 v11 = *(const bf16x8*)(vb + (((16 + lr) * 128 + 64 + lg * 16) ^ vswz));
      acc0 = mfma16(v00, pf0, acc0);
      acc1 = mfma16(v10, pf0, acc1);
      lacc = mfma16(ones, pf0, lacc);
      acc0 = mfma16(v01, pf1, acc0);
      acc1 = mfma16(v11, pf1, acc1);
      lacc = mfma16(ones, pf1, lacc);
    }
    // softmax(t+1) + P(t+1) write (after PV(t) read P(t): per-wave in-order DS)
    if (hn) softmax_p();
  }

  // store unnormalized O^T partials, layout [h][sp][cg(8)][s][4] bf16
  bf16* base = accP + (size_t)(h * NSPLIT + sp) * 8 * NS * 4;
  size_t qrow = qrow0 + lr;
  bf16x4 o0, o1;
  #pragma unroll
  for (int r = 0; r < 4; ++r) { o0[r] = (bf16)acc0[r]; o1[r] = (bf16)acc1[r]; }
  *(bf16x4*)(base + ((size_t)lg * NS + qrow) * 4)       = o0;
  *(bf16x4*)(base + ((size_t)(4 + lg) * NS + qrow) * 4) = o1;
  if (lg == 0)
    ml[(size_t)(h * NSPLIT + sp) * NS + qrow] = lacc[0];   // all rows identical
}

// ---- fused combine (plain sum: fixed-m) + proj GEMM + bias + residual + mask ----
__global__ __launch_bounds__(256) void k_proj(
    const bf16* __restrict__ wp, const bf16* __restrict__ accP, const float* __restrict__ ml,
    const float* __restrict__ proj_b, const float* __restrict__ x,
    const float* __restrict__ mask, float* __restrict__ out) {
  int ot = blockIdx.x;            // 0..1
  int st = blockIdx.y;            // 0..95
  int tid = threadIdx.x;
  __shared__ __align__(16) char at[64 * 256];   // swizzled [s][c] bf16 tile

  int s_local = tid & 63;
  int s = st * 64 + s_local;
  int wk = tid >> 6;
  if (ot == 0 && tid < 64)        // mask passthrough (second output)
    out[(size_t)NC * NS + st * 64 + tid] = mask[st * 64 + tid];
  #pragma unroll
  for (int i = 0; i < 4; ++i) {
    int c0 = (wk * 4 + i) * 8;
    int h = c0 >> 5;
    float L = 0.f;
    #pragma unroll
    for (int spl = 0; spl < NSPLIT; ++spl)
      L += ml[(size_t)(h * NSPLIT + spl) * NS + s];
    float inv = 1.0f / L;
    float o[8] = {};
    int cg0 = (c0 & 31) >> 2;
    #pragma unroll
    for (int spl = 0; spl < NSPLIT; ++spl) {
      const bf16* bp = accP + ((size_t)((h * NSPLIT + spl) * 8 + cg0) * NS + s) * 4;
      bf16x4 a0 = *(const bf16x4*)(bp);
      bf16x4 a1 = *(const bf16x4*)(bp + (size_t)NS * 4);
      #pragma unroll
      for (int j = 0; j < 4; ++j) {
        o[j]     += (float)a0[j];
        o[4 + j] += (float)a1[j];
      }
    }
    bf16x8 ov;
    #pragma unroll
    for (int j = 0; j < 8; ++j) ov[j] = (bf16)(o[j] * inv);
    *(bf16x8*)(at + ((s_local * 256 + c0 * 2) ^ ((s_local & 7) << 4))) = ov;
  }
  __syncthreads();

  int w = tid >> 6, l = tid & 63;
  int lr = l & 15, lg = l >> 4;
  int o_base = ot * 64 + (w >> 1) * 32;
  int sl_base = (w & 1) * 32;
  f32x4 acc[2][2] = {};
  #pragma unroll
  for (int k0 = 0; k0 < NC; k0 += 32) {
    bf16x8 a[2], b[2];
    #pragma unroll
    for (int m = 0; m < 2; ++m)
      a[m] = *(const bf16x8*)(wp + (size_t)(o_base + m * 16 + lr) * NC + k0 + lg * 8);
    #pragma unroll
    for (int n = 0; n < 2; ++n) {
      int row = sl_base + n * 16 + lr;
      b[n] = *(const bf16x8*)(at + ((row * 256 + (k0 + lg * 8) * 2) ^ ((row & 7) << 4)));
    }
    #pragma unroll
    for (int m = 0; m < 2; ++m)
      #pragma unroll
      for (int n = 0; n < 2; ++n)
        acc[m][n] = mfma16(a[m], b[n], acc[m][n]);
  }
  #pragma unroll
  for (int m = 0; m < 2; ++m)
    #pragma unroll
    for (int n = 0; n < 2; ++n)
      #pragma unroll
      for (int r = 0; r < 4; ++r) {
        int o = o_base + m * 16 + lg * 4 + r;
        int sg = st * 64 + sl_base + n * 16 + lr;
        float v = acc[m][n][r] + proj_b[o] + x[(size_t)o * NS + sg];
        out[(size_t)o * NS + sg] = v * mask[sg];
      }
}

extern "C" void kernel_launch(void* const* d_in, const int* in_sizes, int n_in,
                              void* d_out, int out_size, void* d_ws, size_t ws_size,
                              hipStream_t stream) {
  const float* x      = (const float*)d_in[0];
  const float* mask   = (const float*)d_in[1];
  const float* gn_w   = (const float*)d_in[2];
  const float* gn_b   = (const float*)d_in[3];
  const float* qkv_w  = (const float*)d_in[4];
  const float* qkv_b  = (const float*)d_in[5];
  const float* proj_w = (const float*)d_in[6];
  const float* proj_b = (const float*)d_in[7];

  char* ws = (char*)d_ws;
  float* partials = (float*)(ws + 0);            //     768 B
  float* bias_s   = (float*)(ws + 1024);         //    1536 B
  bf16*  wq       = (bf16*)(ws + 4096);          //   98304 B
  bf16*  wp       = (bf16*)(ws + 102400);        //   32768 B
  bf16*  qg       = (bf16*)(ws + 135168);        // 1.50 MB [h][s][32]
  bf16*  kg       = (bf16*)(ws + 1708032);       // 1.50 MB [h][s][32]
  bf16*  vtg      = (bf16*)(ws + 3280896);       // 1.50 MB [h][c][s]
  bf16*  accP     = (bf16*)(ws + 4853760);       // 6.29 MB [h][sp][cg][s][4]
  float* ml       = (float*)(ws + 11145216);     // 393 KB  [h][sp][s]
  float* out      = (float*)d_out;

  k_prep_stats<<<288, 256, 0, stream>>>(qkv_w, qkv_b, proj_w, x, wq, wp, bias_s, partials);
  k_qkv       <<<dim3(6, 96), 256, 0, stream>>>(x, partials, gn_w, gn_b, wq, bias_s, qg, kg, vtg);
  k_attn      <<<dim3(96, 4, NSPLIT), 256, 0, stream>>>(qg, kg, vtg, accP, ml);
  k_proj      <<<dim3(2, 96), 256, 0, stream>>>(wp, accP, ml, proj_b, x, mask, out);
}